// Round 2
// baseline (162.455 us; speedup 1.0000x reference)
//
#include <hip/hip_runtime.h>

#define NL   128   // rows per line table
#define CL   32    // channels per line table
#define HDIM 128   // hidden dim
#define GRID1 1024 // blocks in mask kernel

// ws layout: unsigned long long partials[6][GRID1]
//   word w of block b at partials[w*GRID1 + b]
//   words: 0=x_lo 1=x_hi 2=y_lo 3=y_hi 4=z_lo 5=z_hi

__global__ __launch_bounds__(256) void mask_partial_fill_kernel(
    const float* __restrict__ coords, long long nflt,
    const float* __restrict__ b1, const float* __restrict__ w2,
    const float* __restrict__ b2,
    unsigned long long* __restrict__ partials,
    float* __restrict__ out, int out_n)
{
    const int tid = threadIdx.x;
    const int gid = blockIdx.x * blockDim.x + tid;
    const int nthreads = gridDim.x * blockDim.x;
    const int lane = tid & 63;
    const int wave = tid >> 6;

    unsigned long long mx0 = 0, mx1 = 0, my0 = 0, my1 = 0, mz0 = 0, mz1 = 0;

    const float4* c4 = (const float4*)coords;
    const long long n4 = nflt >> 2;            // number of float4s
    const long long n4tri = (n4 / 3) * 3;      // full 3-float4 (12-float) groups

    // Each thread consumes 3 consecutive float4s (= 4 xyz triples) per iter,
    // so the dim of element e is the compile-time constant e % 3.
    for (long long base = (long long)gid * 3; base + 2 < n4tri;
         base += (long long)nthreads * 3) {
        float4 a = c4[base + 0];
        float4 b = c4[base + 1];
        float4 c = c4[base + 2];
        float v[12] = {a.x, a.y, a.z, a.w, b.x, b.y, b.z, b.w, c.x, c.y, c.z, c.w};
        #pragma unroll
        for (int e = 0; e < 12; ++e) {
            float fi = rintf((v[e] + 2.0f) * 32.0f);   // (x + D/2)*(Nl/D), half-to-even
            bool valid = (fi >= 0.0f) && (fi < 128.0f);
            int idx = (int)fi;
            unsigned long long bit = 1ull << (idx & 63);
            unsigned long long blo = (valid && idx < 64) ? bit : 0ull;
            unsigned long long bhi = (valid && idx >= 64) ? bit : 0ull;
            if (e % 3 == 0)      { mx0 |= blo; mx1 |= bhi; }
            else if (e % 3 == 1) { my0 |= blo; my1 |= bhi; }
            else                 { mz0 |= blo; mz1 |= bhi; }
        }
    }
    // Tail (not hit for the fixed problem size, kept for robustness).
    for (long long f = n4tri * 4 + gid; f < nflt; f += nthreads) {
        float fi = rintf((coords[f] + 2.0f) * 32.0f);
        bool valid = (fi >= 0.0f) && (fi < 128.0f);
        int idx = (int)fi;
        unsigned long long bit = 1ull << (idx & 63);
        unsigned long long blo = (valid && idx < 64) ? bit : 0ull;
        unsigned long long bhi = (valid && idx >= 64) ? bit : 0ull;
        int d = (int)(f % 3);
        if (d == 0)      { mx0 |= blo; mx1 |= bhi; }
        else if (d == 1) { my0 |= blo; my1 |= bhi; }
        else             { mz0 |= blo; mz1 |= bhi; }
    }

    // Butterfly OR-reduce across the 64-lane wave.
    #pragma unroll
    for (int off = 1; off < 64; off <<= 1) {
        mx0 |= __shfl_xor(mx0, off);
        mx1 |= __shfl_xor(mx1, off);
        my0 |= __shfl_xor(my0, off);
        my1 |= __shfl_xor(my1, off);
        mz0 |= __shfl_xor(mz0, off);
        mz1 |= __shfl_xor(mz1, off);
    }

    __shared__ unsigned long long sm[4][6];
    if (lane == 0) {
        sm[wave][0] = mx0; sm[wave][1] = mx1;
        sm[wave][2] = my0; sm[wave][3] = my1;
        sm[wave][4] = mz0; sm[wave][5] = mz1;
    }
    __syncthreads();
    if (tid < 6) {
        // Plain store to this block's private slot — no atomics, no init needed.
        unsigned long long r = sm[0][tid] | sm[1][tid] | sm[2][tid] | sm[3][tid];
        partials[tid * gridDim.x + blockIdx.x] = r;
    }

    // Constant for rows >= NL: b2 + sum_j relu(b1[j]) * w2[j]
    float p = fmaxf(b1[lane], 0.0f) * w2[lane]
            + fmaxf(b1[lane + 64], 0.0f) * w2[lane + 64];
    #pragma unroll
    for (int off = 1; off < 64; off <<= 1) p += __shfl_xor(p, off);
    const float constant = p + b2[0];

    // Fill out[NL..out_n) with the constant (float4 stores; NL % 4 == 0).
    const int n4o = (out_n - NL) >> 2;
    float4* o4 = (float4*)(out + NL);
    const float4 cv = make_float4(constant, constant, constant, constant);
    for (int i = gid; i < n4o; i += nthreads) o4[i] = cv;
    for (int i = NL + (n4o << 2) + gid; i < out_n; i += nthreads) out[i] = constant;
}

__global__ __launch_bounds__(1024) void head_kernel(
    const unsigned long long* __restrict__ partials, int G,
    const float* __restrict__ l0, const float* __restrict__ l1,
    const float* __restrict__ l2,
    const float* __restrict__ w1, const float* __restrict__ b1,
    const float* __restrict__ w2, const float* __restrict__ b2,
    float* __restrict__ out)
{
    const int tid = threadIdx.x;          // 0..1023, one block
    const int lane = tid & 63;
    const int wave = tid >> 6;            // 0..15

    // Phase A: OR-reduce partials[6][G] to a full mask in every thread.
    unsigned long long m[6];
    #pragma unroll
    for (int w = 0; w < 6; ++w) {
        unsigned long long v = 0;
        for (int i = tid; i < G; i += 1024) v |= partials[(long long)w * G + i];
        #pragma unroll
        for (int off = 1; off < 64; off <<= 1) v |= __shfl_xor(v, off);
        m[w] = v;
    }
    __shared__ unsigned long long smw[16][6];
    if (lane == 0) {
        #pragma unroll
        for (int w = 0; w < 6; ++w) smw[wave][w] = m[w];
    }
    __syncthreads();
    #pragma unroll
    for (int w = 0; w < 6; ++w) {
        unsigned long long v = 0;
        #pragma unroll
        for (int q = 0; q < 16; ++q) v |= smw[q][w];   // broadcast reads, no conflict
        m[w] = v;
    }

    // Phase B: MLP on rows 0..127, 8 threads per row.
    const int r = tid >> 3;   // 0..127
    const int g = tid & 7;

    const int word = r >> 6;
    const int bit = r & 63;
    const float ox = (float)((m[0 + word] >> bit) & 1ull);
    const float oy = (float)((m[2 + word] >> bit) & 1ull);
    const float oz = (float)((m[4 + word] >> bit) & 1ull);

    const float R  = 0.4f;
    const float R2 = (float)(0.4 * 0.4);

    float feats[CL];
    #pragma unroll
    for (int c = 0; c < CL; ++c) {
        float x = l0[r * CL + c] * ox;
        float y = l1[r * CL + c] * oy;
        float z = l2[r * CL + c] * oz;
        float f1 = x + y + z;
        float f2 = (x * y + x * z + y * z) / R;
        float f3 = x * y * z / R2;
        feats[c] = f1 + f2 + f3;
    }

    float partial = 0.0f;
    #pragma unroll 4
    for (int j = g; j < HDIM; j += 8) {
        float acc = b1[j];
        #pragma unroll
        for (int c = 0; c < CL; ++c) acc += feats[c] * w1[j * CL + c];
        partial += fmaxf(acc, 0.0f) * w2[j];
    }
    partial += __shfl_xor(partial, 1);
    partial += __shfl_xor(partial, 2);
    partial += __shfl_xor(partial, 4);
    if (g == 0) out[r] = partial + b2[0];
}

extern "C" void kernel_launch(void* const* d_in, const int* in_sizes, int n_in,
                              void* d_out, int out_size, void* d_ws, size_t ws_size,
                              hipStream_t stream) {
    const float* coords = (const float*)d_in[0];
    const float* l0 = (const float*)d_in[1];
    const float* l1 = (const float*)d_in[2];
    const float* l2 = (const float*)d_in[3];
    const float* w1 = (const float*)d_in[4];
    const float* b1 = (const float*)d_in[5];
    const float* w2 = (const float*)d_in[6];
    const float* b2 = (const float*)d_in[7];
    float* out = (float*)d_out;
    unsigned long long* partials = (unsigned long long*)d_ws;
    const long long nflt = (long long)in_sizes[0];

    mask_partial_fill_kernel<<<GRID1, 256, 0, stream>>>(coords, nflt, b1, w2, b2,
                                                        partials, out, out_size);
    head_kernel<<<1, 1024, 0, stream>>>(partials, GRID1, l0, l1, l2,
                                        w1, b1, w2, b2, out);
}

// Round 3
// 105.007 us; speedup vs baseline: 1.5471x; 1.5471x over previous
//
#include <hip/hip_runtime.h>

#define NL   128   // rows per line table
#define CL   32    // channels per line table
#define HDIM 128   // hidden dim
#define GRID1 1024 // blocks in mask kernel

// ws layout: unsigned long long partials[6][GRID1]
//   word w of block b at partials[w*GRID1 + b]
//   words: 0=x_lo 1=x_hi 2=y_lo 3=y_hi 4=z_lo 5=z_hi

__global__ __launch_bounds__(256) void mask_partial_fill_kernel(
    const float* __restrict__ coords, long long nflt,
    const float* __restrict__ b1, const float* __restrict__ w2,
    const float* __restrict__ b2,
    unsigned long long* __restrict__ partials,
    float* __restrict__ out, int out_n)
{
    const int tid = threadIdx.x;
    const int gid = blockIdx.x * blockDim.x + tid;
    const int nthreads = gridDim.x * blockDim.x;
    const int lane = tid & 63;
    const int wave = tid >> 6;

    unsigned long long mx0 = 0, mx1 = 0, my0 = 0, my1 = 0, mz0 = 0, mz1 = 0;

    const float4* c4 = (const float4*)coords;
    const long long n4 = nflt >> 2;            // number of float4s
    const long long n4tri = (n4 / 3) * 3;      // full 3-float4 (12-float) groups

    // Each thread consumes 3 consecutive float4s (= 4 xyz triples) per iter,
    // so the dim of element e is the compile-time constant e % 3.
    for (long long base = (long long)gid * 3; base + 2 < n4tri;
         base += (long long)nthreads * 3) {
        float4 a = c4[base + 0];
        float4 b = c4[base + 1];
        float4 c = c4[base + 2];
        float v[12] = {a.x, a.y, a.z, a.w, b.x, b.y, b.z, b.w, c.x, c.y, c.z, c.w};
        #pragma unroll
        for (int e = 0; e < 12; ++e) {
            float fi = rintf((v[e] + 2.0f) * 32.0f);   // (x + D/2)*(Nl/D), half-to-even
            bool valid = (fi >= 0.0f) && (fi < 128.0f);
            int idx = (int)fi;
            unsigned long long bit = 1ull << (idx & 63);
            unsigned long long blo = (valid && idx < 64) ? bit : 0ull;
            unsigned long long bhi = (valid && idx >= 64) ? bit : 0ull;
            if (e % 3 == 0)      { mx0 |= blo; mx1 |= bhi; }
            else if (e % 3 == 1) { my0 |= blo; my1 |= bhi; }
            else                 { mz0 |= blo; mz1 |= bhi; }
        }
    }
    // Tail (not hit for the fixed problem size, kept for robustness).
    for (long long f = n4tri * 4 + gid; f < nflt; f += nthreads) {
        float fi = rintf((coords[f] + 2.0f) * 32.0f);
        bool valid = (fi >= 0.0f) && (fi < 128.0f);
        int idx = (int)fi;
        unsigned long long bit = 1ull << (idx & 63);
        unsigned long long blo = (valid && idx < 64) ? bit : 0ull;
        unsigned long long bhi = (valid && idx >= 64) ? bit : 0ull;
        int d = (int)(f % 3);
        if (d == 0)      { mx0 |= blo; mx1 |= bhi; }
        else if (d == 1) { my0 |= blo; my1 |= bhi; }
        else             { mz0 |= blo; mz1 |= bhi; }
    }

    // Butterfly OR-reduce across the 64-lane wave.
    #pragma unroll
    for (int off = 1; off < 64; off <<= 1) {
        mx0 |= __shfl_xor(mx0, off);
        mx1 |= __shfl_xor(mx1, off);
        my0 |= __shfl_xor(my0, off);
        my1 |= __shfl_xor(my1, off);
        mz0 |= __shfl_xor(mz0, off);
        mz1 |= __shfl_xor(mz1, off);
    }

    __shared__ unsigned long long sm[4][6];
    if (lane == 0) {
        sm[wave][0] = mx0; sm[wave][1] = mx1;
        sm[wave][2] = my0; sm[wave][3] = my1;
        sm[wave][4] = mz0; sm[wave][5] = mz1;
    }
    __syncthreads();
    if (tid < 6) {
        // Plain store to this block's private slot — no atomics, no init needed.
        unsigned long long r = sm[0][tid] | sm[1][tid] | sm[2][tid] | sm[3][tid];
        partials[tid * gridDim.x + blockIdx.x] = r;
    }

    // Constant for rows >= NL: b2 + sum_j relu(b1[j]) * w2[j]
    float p = fmaxf(b1[lane], 0.0f) * w2[lane]
            + fmaxf(b1[lane + 64], 0.0f) * w2[lane + 64];
    #pragma unroll
    for (int off = 1; off < 64; off <<= 1) p += __shfl_xor(p, off);
    const float constant = p + b2[0];

    // Fill out[NL..out_n) with the constant (float4 stores; NL % 4 == 0).
    const int n4o = (out_n - NL) >> 2;
    float4* o4 = (float4*)(out + NL);
    const float4 cv = make_float4(constant, constant, constant, constant);
    for (int i = gid; i < n4o; i += nthreads) o4[i] = cv;
    for (int i = NL + (n4o << 2) + gid; i < out_n; i += nthreads) out[i] = constant;
}

// One block per output row r (128 blocks, 128 threads = 2 waves).
// Thread j computes hidden unit j; block OR-reduces only the 3 mask words
// its row needs, then reduces the 128 relu(h)*w2 terms to out[r].
__global__ __launch_bounds__(128) void head_kernel(
    const unsigned long long* __restrict__ partials, int G,
    const float* __restrict__ l0, const float* __restrict__ l1,
    const float* __restrict__ l2,
    const float* __restrict__ w1, const float* __restrict__ b1,
    const float* __restrict__ w2, const float* __restrict__ b2,
    float* __restrict__ out)
{
    const int r = blockIdx.x;        // 0..127
    const int tid = threadIdx.x;     // 0..127 (= hidden unit j)
    const int lane = tid & 63;
    const int wave = tid >> 6;       // 0..1

    const int word = r >> 6;
    const int bit = r & 63;

    // Phase A: OR-reduce the 3 words this row needs over G block-partials.
    unsigned long long vx = 0, vy = 0, vz = 0;
    for (int i = tid; i < G; i += 128) {
        vx |= partials[(0 + word) * G + i];
        vy |= partials[(2 + word) * G + i];
        vz |= partials[(4 + word) * G + i];
    }
    #pragma unroll
    for (int off = 1; off < 64; off <<= 1) {
        vx |= __shfl_xor(vx, off);
        vy |= __shfl_xor(vy, off);
        vz |= __shfl_xor(vz, off);
    }
    __shared__ unsigned long long sred[2][3];
    __shared__ float fsum[2];
    if (lane == 0) { sred[wave][0] = vx; sred[wave][1] = vy; sred[wave][2] = vz; }
    __syncthreads();
    vx = sred[0][0] | sred[1][0];
    vy = sred[0][1] | sred[1][1];
    vz = sred[0][2] | sred[1][2];

    const float ox = (float)((vx >> bit) & 1ull);
    const float oy = (float)((vy >> bit) & 1ull);
    const float oz = (float)((vz >> bit) & 1ull);

    const float R  = 0.4f;
    const float R2 = (float)(0.4 * 0.4);

    // feats: every thread computes the same 32 values (broadcast float4 loads).
    float feats[CL];
    const float4* l0v = (const float4*)(l0 + r * CL);
    const float4* l1v = (const float4*)(l1 + r * CL);
    const float4* l2v = (const float4*)(l2 + r * CL);
    #pragma unroll
    for (int c4 = 0; c4 < CL / 4; ++c4) {
        float4 a = l0v[c4];
        float4 b = l1v[c4];
        float4 c = l2v[c4];
        float xs[4] = {a.x * ox, a.y * ox, a.z * ox, a.w * ox};
        float ys[4] = {b.x * oy, b.y * oy, b.z * oy, b.w * oy};
        float zs[4] = {c.x * oz, c.y * oz, c.z * oz, c.w * oz};
        #pragma unroll
        for (int q = 0; q < 4; ++q) {
            float x = xs[q], y = ys[q], z = zs[q];
            float f1 = x + y + z;
            float f2 = (x * y + x * z + y * z) / R;
            float f3 = x * y * z / R2;
            feats[c4 * 4 + q] = f1 + f2 + f3;
        }
    }

    // Hidden unit j = tid: dot(feats, w1[j,:]) + b1[j], relu, * w2[j].
    const float4* w1v = (const float4*)(w1 + tid * CL);
    float acc = b1[tid];
    #pragma unroll
    for (int c4 = 0; c4 < CL / 4; ++c4) {
        float4 w = w1v[c4];
        acc += feats[c4 * 4 + 0] * w.x;
        acc += feats[c4 * 4 + 1] * w.y;
        acc += feats[c4 * 4 + 2] * w.z;
        acc += feats[c4 * 4 + 3] * w.w;
    }
    float h = fmaxf(acc, 0.0f) * w2[tid];

    // Reduce 128 values: 64-lane butterfly + cross-wave via LDS.
    #pragma unroll
    for (int off = 1; off < 64; off <<= 1) h += __shfl_xor(h, off);
    if (lane == 0) fsum[wave] = h;
    __syncthreads();
    if (tid == 0) out[r] = fsum[0] + fsum[1] + b2[0];
}

extern "C" void kernel_launch(void* const* d_in, const int* in_sizes, int n_in,
                              void* d_out, int out_size, void* d_ws, size_t ws_size,
                              hipStream_t stream) {
    const float* coords = (const float*)d_in[0];
    const float* l0 = (const float*)d_in[1];
    const float* l1 = (const float*)d_in[2];
    const float* l2 = (const float*)d_in[3];
    const float* w1 = (const float*)d_in[4];
    const float* b1 = (const float*)d_in[5];
    const float* w2 = (const float*)d_in[6];
    const float* b2 = (const float*)d_in[7];
    float* out = (float*)d_out;
    unsigned long long* partials = (unsigned long long*)d_ws;
    const long long nflt = (long long)in_sizes[0];

    mask_partial_fill_kernel<<<GRID1, 256, 0, stream>>>(coords, nflt, b1, w2, b2,
                                                        partials, out, out_size);
    head_kernel<<<NL, 128, 0, stream>>>(partials, GRID1, l0, l1, l2,
                                        w1, b1, w2, b2, out);
}